// Round 2
// baseline (464.457 us; speedup 1.0000x reference)
//
#include <hip/hip_runtime.h>
#include <stdint.h>

#define H8 64
#define W8 64
#define NB 4
#define NC 256
#define TC 5440   // cells per batch across all 4 levels: 4096+1024+256+64

typedef short bf16x8 __attribute__((ext_vector_type(8)));
typedef float f32x4  __attribute__((ext_vector_type(4)));

__device__ __forceinline__ unsigned short f2b(float x){
  uint32_t u = __float_as_uint(x);
  uint32_t r = (u + 0x7FFFu + ((u >> 16) & 1u)) >> 16;   // RNE to bf16
  return (unsigned short)r;
}
__device__ __forceinline__ float b2f(unsigned short u){
  return __uint_as_float(((uint32_t)u) << 16);
}

// Transpose [b][c][p] fp32 -> [b][p][c] bf16 for f1 (z<4) and f2 level-0 (z>=4).
__global__ void transpose_cvt(const float* __restrict__ f1, const float* __restrict__ f2,
                              unsigned short* __restrict__ f1t, unsigned short* __restrict__ f2p){
  __shared__ float tile[32][33];
  const int z = blockIdx.z; const int bb = z & 3;
  const float* src = (z < 4) ? f1 : f2;
  const int p0 = blockIdx.x * 32, c0 = blockIdx.y * 32;
  const int tx = threadIdx.x, ty = threadIdx.y;   // block (32,8)
  #pragma unroll
  for (int r = 0; r < 4; ++r){
    int c = c0 + ty + r*8;
    tile[ty + r*8][tx] = src[((size_t)bb*NC + c)*4096 + p0 + tx];
  }
  __syncthreads();
  unsigned short* dst = (z < 4) ? f1t : f2p;
  #pragma unroll
  for (int r = 0; r < 4; ++r){
    int p = p0 + ty + r*8;
    size_t o = (z < 4) ? ((size_t)(bb*4096 + p))*NC : ((size_t)(bb*TC + p))*NC;
    dst[o + c0 + tx] = f2b(tile[tx][ty + r*8]);
  }
}

// Pool levels 1..3 directly from level 0 (one launch, no chain; single bf16 round).
// One block = one (batch, cell): 256 threads = 256 channels.
__global__ void pool_all(unsigned short* __restrict__ f2p){
  const int c = threadIdx.x;
  const int rest = blockIdx.x;          // bb*1344 + cell index across levels 1..3
  const int bb = rest / 1344;
  const int cell = rest - bb*1344;
  int lw, k, off, out_cell;
  if (cell < 1024)      { k = 1; off = cell;        lw = 5; out_cell = 4096 + off; }
  else if (cell < 1280) { k = 2; off = cell - 1024; lw = 4; out_cell = 5120 + off; }
  else                  { k = 3; off = cell - 1280; lw = 3; out_cell = 5376 + off; }
  const int u = off >> lw, v = off & ((1 << lw) - 1);
  const int m = 1 << k;
  const unsigned short* base = f2p + ((size_t)bb*TC)*NC + c;
  float s = 0.0f;
  for (int a = 0; a < m; ++a)
    for (int b2 = 0; b2 < m; ++b2)
      s += b2f(base[(size_t)((u*m + a)*64 + (v*m + b2))*NC]);
  f2p[((size_t)bb*TC + out_cell)*NC + c] = f2b(s / (float)(m*m));
}

// Block = one query pixel; wave w = pyramid level w. Per wave: MFMA-compute a
// 10x10 corr box (16 cells/pass, dual acc chains), then 41 bilinear taps.
__global__ __launch_bounds__(256, 4) void lookup_main(const float* __restrict__ flow,
                 const unsigned short* __restrict__ f1t,
                 const unsigned short* __restrict__ f2p,
                 float* __restrict__ out){
  const int lane = threadIdx.x & 63;
  const int wid  = threadIdx.x >> 6;             // = pyramid level k
  // XCD swizzle: blockIdx%8 -> (batch, parity); one batch's pooled f2 per 2 XCDs
  const int Bk = blockIdx.x;
  const int xs = Bk & 7;
  const int bb = xs >> 1;
  const int pix = ((Bk >> 3) << 1) | (xs & 1);   // 0..4095
  const int i = pix >> 6, j = pix & 63;

  __shared__ __align__(16) unsigned short f1s[NC];
  __shared__ float box[4][112];

  if (threadIdx.x < 64){
    const unsigned short* f1c = f1t + ((size_t)(bb*4096 + pix))*NC;
    ((uint2*)f1s)[threadIdx.x] = ((const uint2*)f1c)[threadIdx.x];  // 512B column
  }
  const float fy = flow[((bb*2 + 0)*H8 + i)*W8 + j];
  const float fx = flow[((bb*2 + 1)*H8 + i)*W8 + j];
  __syncthreads();

  // diamond offset (dy,dx) for tap t = lane (lane < 41), reference order
  int dy = 0, dx = 0;
  {
    int rem = lane;
    #pragma unroll
    for (int ry = -4; ry <= 4; ++ry){
      int ab = ry < 0 ? -ry : ry;
      int ln = 9 - 2*ab;
      if (rem >= 0 && rem < ln){ dy = ry; dx = rem + (ab - 4); }
      rem -= ln;
    }
  }

  const int k = wid;
  const int h = H8 >> k;
  const float inv = ldexpf(1.0f, -k);
  const float s = (float)(h - 1) / (float)h;
  const float yc = ((float)i + fy) * inv;
  const float xc = ((float)j + fx) * inv;
  const int y0b = (int)floorf((yc - 4.0f) * s);
  const int x0b = (int)floorf((xc - 4.0f) * s);
  const int lvo = (k == 0) ? 0 : (k == 1) ? 4096 : (k == 2) ? 5120 : 5376;
  const unsigned short* lv = f2p + ((size_t)bb*TC + lvo)*NC;

  const int g    = lane >> 4;    // k-chunk group 0..3
  const int mrow = lane & 15;    // A-row = cell within pass

  #pragma unroll
  for (int p = 0; p < 7; ++p){
    const int cp = p*16 + mrow;            // cell 0..111 in 10x10(+pad) box
    const int ca = (cp * 205) >> 11;       // == cp/10 for cp < 1029
    const int cb = cp - ca*10;
    const int gy = y0b + ca, gx = x0b + cb;
    const int gyc = min(max(gy, 0), h-1);
    const int gxc = min(max(gx, 0), h-1);
    const unsigned short* col = lv + (size_t)(gyc*h + gxc)*NC;
    f32x4 acc0 = {0.f, 0.f, 0.f, 0.f};
    f32x4 acc1 = {0.f, 0.f, 0.f, 0.f};
    #pragma unroll
    for (int st = 0; st < 8; st += 2){
      const int ch0 = st*32 + g*8;
      const int ch1 = ch0 + 32;
      bf16x8 a0 = *(const bf16x8*)(col + ch0);
      bf16x8 a1 = *(const bf16x8*)(col + ch1);
      bf16x8 b0 = *(const bf16x8*)(&f1s[ch0]);
      bf16x8 b1 = *(const bf16x8*)(&f1s[ch1]);
      acc0 = __builtin_amdgcn_mfma_f32_16x16x32_bf16(a0, b0, acc0, 0, 0, 0);
      acc1 = __builtin_amdgcn_mfma_f32_16x16x32_bf16(a1, b1, acc1, 0, 0, 0);
    }
    // C/D: col = lane&15 (we want n=0), row = (lane>>4)*4 + reg  [m89-verified]
    if (mrow == 0){
      #pragma unroll
      for (int r = 0; r < 4; ++r){
        int cq  = p*16 + g*4 + r;
        int ca2 = (cq * 205) >> 11;
        int cb2 = cq - ca2*10;
        int gy2 = y0b + ca2, gx2 = x0b + cb2;
        bool val = (cq < 100) & (gy2 >= 0) & (gy2 < h) & (gx2 >= 0) & (gx2 < h);
        box[wid][cq] = val ? (acc0[r] + acc1[r]) * 0.0625f : 0.0f;  // /sqrt(C)=16
      }
    }
  }
  asm volatile("s_waitcnt lgkmcnt(0)" ::: "memory");
  if (lane < 41){
    float py = (yc + (float)dy) * s;
    float px = (xc + (float)dx) * s;
    float fy0 = floorf(py), fx0 = floorf(px);
    float wy1 = py - fy0, wx1 = px - fx0;
    float wy0 = 1.0f - wy1, wx0 = 1.0f - wx1;
    int iy = (int)fy0 - y0b;
    int ix = (int)fx0 - x0b;
    const float* bx = &box[wid][iy*10 + ix];
    float v = wy0*(wx0*bx[0] + wx1*bx[1]) + wy1*(wx0*bx[10] + wx1*bx[11]);
    out[((size_t)(bb*4096 + pix)*4 + k)*41 + lane] = v;
  }
}

extern "C" void kernel_launch(void* const* d_in, const int* in_sizes, int n_in,
                              void* d_out, int out_size, void* d_ws, size_t ws_size,
                              hipStream_t stream){
  const float* feat1 = (const float*)d_in[0];
  const float* feat2 = (const float*)d_in[1];
  const float* flow  = (const float*)d_in[2];
  float* out = (float*)d_out;
  unsigned short* f1t = (unsigned short*)d_ws;                 // 4*4096*256 bf16 = 8.4 MB
  unsigned short* f2p = f1t + (size_t)NB*4096*NC;              // 4*5440*256 bf16 = 11.1 MB

  transpose_cvt<<<dim3(128, 8, 8), dim3(32, 8, 1), 0, stream>>>(feat1, feat2, f1t, f2p);
  pool_all<<<NB*1344, 256, 0, stream>>>(f2p);
  lookup_main<<<16384, 256, 0, stream>>>(flow, f1t, f2p, out);
}

// Round 3
// 146.870 us; speedup vs baseline: 3.1624x; 3.1624x over previous
//
#include <hip/hip_runtime.h>
#include <stdint.h>

#define NB 4
#define NC 256
#define TC 5440   // cells per batch across levels: 4096+1024+256+64

typedef short bf16x8 __attribute__((ext_vector_type(8)));
typedef float f32x4  __attribute__((ext_vector_type(4)));

__device__ __forceinline__ unsigned short f2b(float x){
  uint32_t u = __float_as_uint(x);
  return (unsigned short)((u + 0x7FFFu + ((u >> 16) & 1u)) >> 16);  // RNE
}
__device__ __forceinline__ float b2f(unsigned short u){
  return __uint_as_float(((uint32_t)u) << 16);
}

// [b][c][p] fp32 -> [b][p][c] bf16; 64ch x 32px tiles, ushort2 stores.
__global__ void transpose_cvt(const float* __restrict__ f1, const float* __restrict__ f2,
                              unsigned short* __restrict__ f1t, unsigned short* __restrict__ f2p){
  __shared__ float tile[64][33];
  const int z = blockIdx.z; const int bb = z & 3;
  const float* src = (z < 4) ? f1 : f2;
  const int p0 = blockIdx.x * 32, c0 = blockIdx.y * 64;
  const int tx = threadIdx.x, ty = threadIdx.y;   // block (32,8)
  #pragma unroll
  for (int r = 0; r < 8; ++r){
    int c = ty + r*8;
    tile[c][tx] = src[((size_t)bb*NC + c0 + c)*4096 + p0 + tx];
  }
  __syncthreads();
  unsigned short* dst = (z < 4) ? f1t : f2p;
  #pragma unroll
  for (int r = 0; r < 4; ++r){
    int pl = ty + r*8;                 // 0..31
    int p  = p0 + pl;
    size_t o = (z < 4) ? ((size_t)(bb*4096 + p))*NC : ((size_t)bb*TC + p)*NC;
    unsigned int v = (unsigned int)f2b(tile[2*tx][pl])
                   | ((unsigned int)f2b(tile[2*tx+1][pl]) << 16);
    *(unsigned int*)(dst + o + c0 + 2*tx) = v;   // 4B stores, coalesced in pairs
  }
}

// Pool levels 1..3 directly from level 0 (one launch, single bf16 round).
__global__ void pool_all(unsigned short* __restrict__ f2p){
  const int c = threadIdx.x;
  const int rest = blockIdx.x;
  const int bb = rest / 1344;
  const int cell = rest - bb*1344;
  int lw, k, off, out_cell;
  if (cell < 1024)      { k = 1; off = cell;        lw = 5; out_cell = 4096 + off; }
  else if (cell < 1280) { k = 2; off = cell - 1024; lw = 4; out_cell = 5120 + off; }
  else                  { k = 3; off = cell - 1280; lw = 3; out_cell = 5376 + off; }
  const int u = off >> lw, v = off & ((1 << lw) - 1);
  const int m = 1 << k;
  const unsigned short* base = f2p + ((size_t)bb*TC)*NC + c;
  float s = 0.0f;
  for (int a = 0; a < m; ++a)
    for (int b2 = 0; b2 < m; ++b2)
      s += b2f(base[(size_t)((u*m + a)*64 + (v*m + b2))*NC]);
  f2p[((size_t)bb*TC + out_cell)*NC + c] = f2b(s / (float)(m*m));
}

// Block = 4x4 pixel tile. Per level: bbox-union of the 16 pixels' 10x10 boxes,
// MFMA corr[16 cells x 16 pixels] over union cells (fetched ONCE per tile),
// scatter C into per-pixel LDS boxes, then 41 bilinear taps per (pixel,level).
__global__ __launch_bounds__(256, 4) void lookup_main(const float* __restrict__ flow,
                 const unsigned short* __restrict__ f1t,
                 const unsigned short* __restrict__ f2p,
                 float* __restrict__ out){
  const int lane = threadIdx.x & 63;
  const int wid  = threadIdx.x >> 6;
  const int blk = blockIdx.x;
  const int xs = blk & 7;                         // XCD swizzle: batch per XCD-pair
  const int bb = xs >> 1;
  const int tile = ((blk >> 3) << 1) | (xs & 1);  // 0..255
  const int ti4 = (tile >> 4) << 2;
  const int tj4 = (tile & 15) << 2;

  __shared__ float box[4*16*112];                 // [level][pixel][10x10+pad], 28.7KB
  __shared__ int   ls_y0[64], ls_x0[64];          // [level][pixel]
  __shared__ float ls_f[32];                      // fy[16], fx[16]
  __shared__ int   ls_meta[32];                   // [level][8]

  {
    float4* b4 = (float4*)box;
    for (int q = threadIdx.x; q < (4*16*112)/4; q += 256)
      b4[q] = make_float4(0.f, 0.f, 0.f, 0.f);
  }

  const int n = lane & 15;                        // MFMA n = pixel column
  const int g = lane >> 4;                        // MFMA k-chunk group
  const int pn = ((ti4 + (n >> 2)) << 6) + tj4 + (n & 3);

  // B fragments: f1 columns of the tile's 16 pixels, once per wave (registers)
  bf16x8 bfr[8];
  {
    const unsigned short* f1c = f1t + ((size_t)(bb*4096 + pn))*NC;
    #pragma unroll
    for (int st = 0; st < 8; ++st)
      bfr[st] = *(const bf16x8*)(f1c + st*32 + g*8);
  }

  if (wid == 0){                                  // lane = k*16 + n
    const int k = g;
    const int i_n = pn >> 6, j_n = pn & 63;
    const float fy = flow[((bb*2 + 0)*64 + i_n)*64 + j_n];
    const float fx = flow[((bb*2 + 1)*64 + i_n)*64 + j_n];
    if (k == 0){ ls_f[n] = fy; ls_f[16 + n] = fx; }
    const int h = 64 >> k;
    const float inv = 1.0f / (float)(1 << k);
    const float s = (float)(h - 1) / (float)h;
    const float yc = ((float)i_n + fy) * inv;
    const float xc = ((float)j_n + fx) * inv;
    const int y0 = (int)floorf((yc - 4.0f) * s);
    const int x0 = (int)floorf((xc - 4.0f) * s);
    ls_y0[k*16 + n] = y0;
    ls_x0[k*16 + n] = x0;
    int ymin = y0, ymax = y0, xmin = x0, xmax = x0;
    #pragma unroll
    for (int m = 1; m < 16; m <<= 1){
      ymin = min(ymin, __shfl_xor(ymin, m));
      ymax = max(ymax, __shfl_xor(ymax, m));
      xmin = min(xmin, __shfl_xor(xmin, m));
      xmax = max(xmax, __shfl_xor(xmax, m));
    }
    if (n == 0){
      int ylo = max(ymin, 0), yhi = min(ymax + 9, h - 1);
      int xlo = max(xmin, 0), xhi = min(xmax + 9, h - 1);
      int H = max(yhi - ylo + 1, 0), W = max(xhi - xlo + 1, 0);
      int cells = W * H;
      ls_meta[k*8 + 0] = ylo;
      ls_meta[k*8 + 1] = xlo;
      ls_meta[k*8 + 2] = W;
      ls_meta[k*8 + 3] = cells;
      ls_meta[k*8 + 4] = __float_as_int(1.0f / (float)W);
      ls_meta[k*8 + 5] = (k==0) ? 0 : (k==1) ? 4096 : (k==2) ? 5120 : 5376;
      ls_meta[k*8 + 6] = (cells + 15) >> 4;       // passes
    }
  }
  __syncthreads();

  const int y0n0 = ls_y0[n],      x0n0 = ls_x0[n];
  const int y0n1 = ls_y0[16 + n], x0n1 = ls_x0[16 + n];
  const int y0n2 = ls_y0[32 + n], x0n2 = ls_x0[32 + n];
  const int y0n3 = ls_y0[48 + n], x0n3 = ls_x0[48 + n];
  const int pre1 = ls_meta[6];
  const int pre2 = pre1 + ls_meta[14];
  const int pre3 = pre2 + ls_meta[22];
  const int P    = pre3 + ls_meta[30];

  for (int p = wid; p < P; p += 4){
    const int k  = (p >= pre1) + (p >= pre2) + (p >= pre3);
    const int lp = p - ((k==0) ? 0 : (k==1) ? pre1 : (k==2) ? pre2 : pre3);
    const int mb = k*8;
    const int ylo = ls_meta[mb], xlo = ls_meta[mb+1], W = ls_meta[mb+2];
    const int cells = ls_meta[mb+3];
    const float rW = __int_as_float(ls_meta[mb+4]);
    const int lvo = ls_meta[mb+5];
    const int h = 64 >> k;
    const int base = lp << 4;

    const int idxA = min(base + n, cells - 1);
    const int by = (int)fmaf((float)idxA, rW, 0.004f);
    const int bx = idxA - by*W;
    const unsigned short* col = f2p + ((size_t)bb*TC + lvo + (ylo + by)*h + (xlo + bx))*NC;

    f32x4 acc0 = {0.f,0.f,0.f,0.f}, acc1 = {0.f,0.f,0.f,0.f};
    #pragma unroll
    for (int st = 0; st < 8; st += 2){
      bf16x8 a0 = *(const bf16x8*)(col + st*32 + g*8);
      bf16x8 a1 = *(const bf16x8*)(col + (st+1)*32 + g*8);
      acc0 = __builtin_amdgcn_mfma_f32_16x16x32_bf16(a0, bfr[st],   acc0, 0, 0, 0);
      acc1 = __builtin_amdgcn_mfma_f32_16x16x32_bf16(a1, bfr[st+1], acc1, 0, 0, 0);
    }
    // C/D: col = lane&15 = pixel n, row = cell = g*4 + r  [m89-verified]
    const int yb = (k==0) ? y0n0 : (k==1) ? y0n1 : (k==2) ? y0n2 : y0n3;
    const int xb = (k==0) ? x0n0 : (k==1) ? x0n1 : (k==2) ? x0n2 : x0n3;
    #pragma unroll
    for (int r = 0; r < 4; ++r){
      const int ci = base + (g << 2) + r;
      if (ci < cells){
        const int byc = (int)fmaf((float)ci, rW, 0.004f);
        const int bxc = ci - byc*W;
        const int ry = ylo + byc - yb;
        const int rx = xlo + bxc - xb;
        if ((unsigned)ry < 10u && (unsigned)rx < 10u)
          box[(k*16 + n)*112 + ry*10 + rx] = (acc0[r] + acc1[r]) * 0.0625f; // /sqrt(256)
      }
    }
  }
  __syncthreads();

  // Tap phase: wave w = level w; 16 pixels sequential, 41 taps in lanes.
  int dy = 0, dx = 0;
  {
    int rem = lane;
    #pragma unroll
    for (int ry = -4; ry <= 4; ++ry){
      int ab = ry < 0 ? -ry : ry;
      int ln = 9 - 2*ab;
      if (rem >= 0 && rem < ln){ dy = ry; dx = rem + (ab - 4); }
      rem -= ln;
    }
  }
  const int k = wid;
  const float inv = 1.0f / (float)(1 << k);
  const float s = (float)((64 >> k) - 1) / (float)(64 >> k);
  if (lane < 41){
    for (int t = 0; t < 16; ++t){
      const int pt = ((ti4 + (t >> 2)) << 6) + tj4 + (t & 3);
      const float fy = ls_f[t], fx = ls_f[16 + t];
      const float yc = ((float)(pt >> 6) + fy) * inv;
      const float xc = ((float)(pt & 63) + fx) * inv;
      const float py = (yc + (float)dy) * s;
      const float px = (xc + (float)dx) * s;
      const float fy0 = floorf(py), fx0 = floorf(px);
      const float wy1 = py - fy0, wx1 = px - fx0;
      const float wy0 = 1.0f - wy1, wx0 = 1.0f - wx1;
      const int iy = (int)fy0 - ls_y0[k*16 + t];
      const int ix = (int)fx0 - ls_x0[k*16 + t];
      const float* bx_ = &box[(k*16 + t)*112 + iy*10 + ix];
      const float v = wy0*(wx0*bx_[0] + wx1*bx_[1]) + wy1*(wx0*bx_[10] + wx1*bx_[11]);
      out[((size_t)(bb*4096 + pt)*4 + k)*41 + lane] = v;
    }
  }
}

extern "C" void kernel_launch(void* const* d_in, const int* in_sizes, int n_in,
                              void* d_out, int out_size, void* d_ws, size_t ws_size,
                              hipStream_t stream){
  const float* feat1 = (const float*)d_in[0];
  const float* feat2 = (const float*)d_in[1];
  const float* flow  = (const float*)d_in[2];
  float* out = (float*)d_out;
  unsigned short* f1t = (unsigned short*)d_ws;                 // 4*4096*256 bf16
  unsigned short* f2p = f1t + (size_t)NB*4096*NC;              // 4*5440*256 bf16

  transpose_cvt<<<dim3(128, 4, 8), dim3(32, 8, 1), 0, stream>>>(feat1, feat2, f1t, f2p);
  pool_all<<<NB*1344, 256, 0, stream>>>(f2p);
  lookup_main<<<1024, 256, 0, stream>>>(flow, f1t, f2p, out);
}

// Round 4
// 125.628 us; speedup vs baseline: 3.6971x; 1.1691x over previous
//
#include <hip/hip_runtime.h>
#include <stdint.h>

#define NB 4
#define NC 256
#define TC 5440   // cells per batch across levels: 4096+1024+256+64

typedef short bf16x8 __attribute__((ext_vector_type(8)));
typedef float f32x4  __attribute__((ext_vector_type(4)));

__device__ __forceinline__ unsigned short f2b(float x){
  uint32_t u = __float_as_uint(x);
  return (unsigned short)((u + 0x7FFFu + ((u >> 16) & 1u)) >> 16);  // RNE
}

// Fused preprocessing:
//  blocks [0,2048):    f1 [b][c][p] fp32 -> f1t [b][p][c] bf16 (64ch x 32px tiles)
//  blocks [2048,2560): f2 8x16-cell region x 64ch chunk -> level0 bf16 cell-major
//                      + levels 1..3 pooled in-LDS (fp32) -> bf16, no extra pass
__global__ __launch_bounds__(256) void prep_all(const float* __restrict__ f1,
                 const float* __restrict__ f2,
                 unsigned short* __restrict__ f1t,
                 unsigned short* __restrict__ f2p){
  __shared__ float lds[128*65];                   // 33.3 KB
  const int t = threadIdx.x;
  const int bx = blockIdx.x;

  if (bx < 2048){
    const int b = bx >> 9, rest = bx & 511;
    const int cc = rest >> 7, pt = rest & 127;
    const int p0 = pt*32, c0 = cc*64;
    const int tx = t & 31, ty = t >> 5;           // (32,8)
    float (*tileF)[33] = (float(*)[33])lds;
    #pragma unroll
    for (int r = 0; r < 8; ++r){
      int c = ty + r*8;
      tileF[c][tx] = f1[((size_t)(b*NC) + c0 + c)*4096 + p0 + tx];
    }
    __syncthreads();
    #pragma unroll
    for (int r = 0; r < 4; ++r){
      int pl = ty + r*8;
      size_t o = ((size_t)(b*4096 + p0 + pl))*NC;
      unsigned int v = (unsigned int)f2b(tileF[2*tx][pl])
                     | ((unsigned int)f2b(tileF[2*tx+1][pl]) << 16);
      *(unsigned int*)(f1t + o + c0 + 2*tx) = v;  // 4B stores, 128B/half-wave
    }
  } else {
    const int fid = bx - 2048;                    // 0..511
    const int b = fid >> 7, rest = fid & 127;
    const int reg = rest >> 2, cc = rest & 3;
    const int i0 = (reg >> 2) * 8, j0 = (reg & 3) * 16;
    const int c0 = cc * 64;

    // Phase 1: fp32 region -> LDS[cell][ch], coalesced 64B row loads
    #pragma unroll
    for (int it = 0; it < 8; ++it){
      int q = t + 256*it;                         // 0..2047
      int ch = q >> 5, rc = q & 31, ri = rc >> 2, c4 = rc & 3;
      const float4 v = *(const float4*)(f2 + ((size_t)(b*NC) + c0 + ch)*4096
                                          + (i0+ri)*64 + j0 + c4*4);
      float* dstL = lds + (ri*16 + c4*4)*65 + ch; // cell stride 65 (pad)
      dstL[0] = v.x; dstL[65] = v.y; dstL[130] = v.z; dstL[195] = v.w;
    }
    __syncthreads();
    unsigned short* f2pB = f2p + (size_t)b*TC*NC;

    // Level 0: 128 cells x 64 ch bf16, cell-major
    {
      const int u = t & 31, cb = t >> 5;
      #pragma unroll
      for (int it = 0; it < 16; ++it){
        int l = cb + 8*it;
        int ci = l >> 4, cj = l & 15;
        unsigned int v = (unsigned int)f2b(lds[l*65 + 2*u])
                       | ((unsigned int)f2b(lds[l*65 + 2*u + 1]) << 16);
        *(unsigned int*)(f2pB + ((size_t)((i0+ci)*64 + j0+cj))*NC + c0 + 2*u) = v;
      }
    }
    // Level 1: 4x8 local cells
    #pragma unroll
    for (int it = 0; it < 8; ++it){
      int idx = t + 256*it;
      int cl = idx >> 6, ch = idx & 63;
      int a = cl >> 3, bc = cl & 7;
      const float* p00 = lds + ((2*a)*16 + 2*bc)*65 + ch;
      float s = p00[0] + p00[65] + p00[16*65] + p00[17*65];
      f2pB[((size_t)(4096 + ((i0>>1)+a)*32 + (j0>>1)+bc))*NC + c0 + ch] = f2b(s*0.25f);
    }
    // Level 2: 2x4 local cells
    #pragma unroll
    for (int it = 0; it < 2; ++it){
      int idx = t + 256*it;
      int cl = idx >> 6, ch = idx & 63;
      int a = cl >> 2, bc = cl & 3;
      float s = 0.f;
      #pragma unroll
      for (int dy2 = 0; dy2 < 4; ++dy2)
        #pragma unroll
        for (int dx2 = 0; dx2 < 4; ++dx2)
          s += lds[((4*a+dy2)*16 + 4*bc+dx2)*65 + ch];
      f2pB[((size_t)(5120 + ((i0>>2)+a)*16 + (j0>>2)+bc))*NC + c0 + ch] = f2b(s*0.0625f);
    }
    // Level 3: 1x2 local cells
    if (t < 128){
      int cl = t >> 6, ch = t & 63;
      float s = 0.f;
      #pragma unroll
      for (int dy3 = 0; dy3 < 8; ++dy3)
        #pragma unroll
        for (int dx3 = 0; dx3 < 8; ++dx3)
          s += lds[(dy3*16 + 8*cl + dx3)*65 + ch];
      f2pB[((size_t)(5376 + (i0>>3)*8 + (j0>>3) + cl))*NC + c0 + ch] = f2b(s*(1.0f/64.0f));
    }
  }
}

// Block = 4x4 pixel tile. Per level: bbox-union of the 16 pixels' 10x10 boxes,
// MFMA corr[16 cells x 16 pixels] over union cells (fetched ONCE per tile),
// scatter C into per-pixel LDS boxes, then 41 bilinear taps per (pixel,level).
// (Byte-identical to R3's verified kernel.)
__global__ __launch_bounds__(256, 4) void lookup_main(const float* __restrict__ flow,
                 const unsigned short* __restrict__ f1t,
                 const unsigned short* __restrict__ f2p,
                 float* __restrict__ out){
  const int lane = threadIdx.x & 63;
  const int wid  = threadIdx.x >> 6;
  const int blk = blockIdx.x;
  const int xs = blk & 7;                         // XCD swizzle: batch per XCD-pair
  const int bb = xs >> 1;
  const int tile = ((blk >> 3) << 1) | (xs & 1);  // 0..255
  const int ti4 = (tile >> 4) << 2;
  const int tj4 = (tile & 15) << 2;

  __shared__ float box[4*16*112];                 // [level][pixel][10x10+pad], 28.7KB
  __shared__ int   ls_y0[64], ls_x0[64];          // [level][pixel]
  __shared__ float ls_f[32];                      // fy[16], fx[16]
  __shared__ int   ls_meta[32];                   // [level][8]

  {
    float4* b4 = (float4*)box;
    for (int q = threadIdx.x; q < (4*16*112)/4; q += 256)
      b4[q] = make_float4(0.f, 0.f, 0.f, 0.f);
  }

  const int n = lane & 15;                        // MFMA n = pixel column
  const int g = lane >> 4;                        // MFMA k-chunk group
  const int pn = ((ti4 + (n >> 2)) << 6) + tj4 + (n & 3);

  // B fragments: f1 columns of the tile's 16 pixels, once per wave (registers)
  bf16x8 bfr[8];
  {
    const unsigned short* f1c = f1t + ((size_t)(bb*4096 + pn))*NC;
    #pragma unroll
    for (int st = 0; st < 8; ++st)
      bfr[st] = *(const bf16x8*)(f1c + st*32 + g*8);
  }

  if (wid == 0){                                  // lane = k*16 + n
    const int k = g;
    const int i_n = pn >> 6, j_n = pn & 63;
    const float fy = flow[((bb*2 + 0)*64 + i_n)*64 + j_n];
    const float fx = flow[((bb*2 + 1)*64 + i_n)*64 + j_n];
    if (k == 0){ ls_f[n] = fy; ls_f[16 + n] = fx; }
    const int h = 64 >> k;
    const float inv = 1.0f / (float)(1 << k);
    const float s = (float)(h - 1) / (float)h;
    const float yc = ((float)i_n + fy) * inv;
    const float xc = ((float)j_n + fx) * inv;
    const int y0 = (int)floorf((yc - 4.0f) * s);
    const int x0 = (int)floorf((xc - 4.0f) * s);
    ls_y0[k*16 + n] = y0;
    ls_x0[k*16 + n] = x0;
    int ymin = y0, ymax = y0, xmin = x0, xmax = x0;
    #pragma unroll
    for (int m = 1; m < 16; m <<= 1){
      ymin = min(ymin, __shfl_xor(ymin, m));
      ymax = max(ymax, __shfl_xor(ymax, m));
      xmin = min(xmin, __shfl_xor(xmin, m));
      xmax = max(xmax, __shfl_xor(xmax, m));
    }
    if (n == 0){
      int ylo = max(ymin, 0), yhi = min(ymax + 9, h - 1);
      int xlo = max(xmin, 0), xhi = min(xmax + 9, h - 1);
      int H = max(yhi - ylo + 1, 0), W = max(xhi - xlo + 1, 0);
      int cells = W * H;
      ls_meta[k*8 + 0] = ylo;
      ls_meta[k*8 + 1] = xlo;
      ls_meta[k*8 + 2] = W;
      ls_meta[k*8 + 3] = cells;
      ls_meta[k*8 + 4] = __float_as_int(1.0f / (float)W);
      ls_meta[k*8 + 5] = (k==0) ? 0 : (k==1) ? 4096 : (k==2) ? 5120 : 5376;
      ls_meta[k*8 + 6] = (cells + 15) >> 4;       // passes
    }
  }
  __syncthreads();

  const int y0n0 = ls_y0[n],      x0n0 = ls_x0[n];
  const int y0n1 = ls_y0[16 + n], x0n1 = ls_x0[16 + n];
  const int y0n2 = ls_y0[32 + n], x0n2 = ls_x0[32 + n];
  const int y0n3 = ls_y0[48 + n], x0n3 = ls_x0[48 + n];
  const int pre1 = ls_meta[6];
  const int pre2 = pre1 + ls_meta[14];
  const int pre3 = pre2 + ls_meta[22];
  const int P    = pre3 + ls_meta[30];

  for (int p = wid; p < P; p += 4){
    const int k  = (p >= pre1) + (p >= pre2) + (p >= pre3);
    const int lp = p - ((k==0) ? 0 : (k==1) ? pre1 : (k==2) ? pre2 : pre3);
    const int mb = k*8;
    const int ylo = ls_meta[mb], xlo = ls_meta[mb+1], W = ls_meta[mb+2];
    const int cells = ls_meta[mb+3];
    const float rW = __int_as_float(ls_meta[mb+4]);
    const int lvo = ls_meta[mb+5];
    const int h = 64 >> k;
    const int base = lp << 4;

    const int idxA = min(base + n, cells - 1);
    const int by = (int)fmaf((float)idxA, rW, 0.004f);
    const int bx = idxA - by*W;
    const unsigned short* col = f2p + ((size_t)bb*TC + lvo + (ylo + by)*h + (xlo + bx))*NC;

    f32x4 acc0 = {0.f,0.f,0.f,0.f}, acc1 = {0.f,0.f,0.f,0.f};
    #pragma unroll
    for (int st = 0; st < 8; st += 2){
      bf16x8 a0 = *(const bf16x8*)(col + st*32 + g*8);
      bf16x8 a1 = *(const bf16x8*)(col + (st+1)*32 + g*8);
      acc0 = __builtin_amdgcn_mfma_f32_16x16x32_bf16(a0, bfr[st],   acc0, 0, 0, 0);
      acc1 = __builtin_amdgcn_mfma_f32_16x16x32_bf16(a1, bfr[st+1], acc1, 0, 0, 0);
    }
    // C/D: col = lane&15 = pixel n, row = cell = g*4 + r  [m89-verified]
    const int yb = (k==0) ? y0n0 : (k==1) ? y0n1 : (k==2) ? y0n2 : y0n3;
    const int xb = (k==0) ? x0n0 : (k==1) ? x0n1 : (k==2) ? x0n2 : x0n3;
    #pragma unroll
    for (int r = 0; r < 4; ++r){
      const int ci = base + (g << 2) + r;
      if (ci < cells){
        const int byc = (int)fmaf((float)ci, rW, 0.004f);
        const int bxc = ci - byc*W;
        const int ry = ylo + byc - yb;
        const int rx = xlo + bxc - xb;
        if ((unsigned)ry < 10u && (unsigned)rx < 10u)
          box[(k*16 + n)*112 + ry*10 + rx] = (acc0[r] + acc1[r]) * 0.0625f; // /sqrt(256)
      }
    }
  }
  __syncthreads();

  // Tap phase: wave w = level w; 16 pixels sequential, 41 taps in lanes.
  int dy = 0, dx = 0;
  {
    int rem = lane;
    #pragma unroll
    for (int ry = -4; ry <= 4; ++ry){
      int ab = ry < 0 ? -ry : ry;
      int ln = 9 - 2*ab;
      if (rem >= 0 && rem < ln){ dy = ry; dx = rem + (ab - 4); }
      rem -= ln;
    }
  }
  const int k = wid;
  const float inv = 1.0f / (float)(1 << k);
  const float s = (float)((64 >> k) - 1) / (float)(64 >> k);
  if (lane < 41){
    for (int t = 0; t < 16; ++t){
      const int pt = ((ti4 + (t >> 2)) << 6) + tj4 + (t & 3);
      const float fy = ls_f[t], fx = ls_f[16 + t];
      const float yc = ((float)(pt >> 6) + fy) * inv;
      const float xc = ((float)(pt & 63) + fx) * inv;
      const float py = (yc + (float)dy) * s;
      const float px = (xc + (float)dx) * s;
      const float fy0 = floorf(py), fx0 = floorf(px);
      const float wy1 = py - fy0, wx1 = px - fx0;
      const float wy0 = 1.0f - wy1, wx0 = 1.0f - wx1;
      const int iy = (int)fy0 - ls_y0[k*16 + t];
      const int ix = (int)fx0 - ls_x0[k*16 + t];
      const float* bx_ = &box[(k*16 + t)*112 + iy*10 + ix];
      const float v = wy0*(wx0*bx_[0] + wx1*bx_[1]) + wy1*(wx0*bx_[10] + wx1*bx_[11]);
      out[((size_t)(bb*4096 + pt)*4 + k)*41 + lane] = v;
    }
  }
}

extern "C" void kernel_launch(void* const* d_in, const int* in_sizes, int n_in,
                              void* d_out, int out_size, void* d_ws, size_t ws_size,
                              hipStream_t stream){
  const float* feat1 = (const float*)d_in[0];
  const float* feat2 = (const float*)d_in[1];
  const float* flow  = (const float*)d_in[2];
  float* out = (float*)d_out;
  unsigned short* f1t = (unsigned short*)d_ws;                 // 4*4096*256 bf16
  unsigned short* f2p = f1t + (size_t)NB*4096*NC;              // 4*5440*256 bf16

  prep_all<<<2560, 256, 0, stream>>>(feat1, feat2, f1t, f2p);
  lookup_main<<<1024, 256, 0, stream>>>(flow, f1t, f2p, out);
}